// Round 8
// baseline (317.746 us; speedup 1.0000x reference)
//
#include <hip/hip_runtime.h>
#include <float.h>

#define KCODES 512
#define GDIM 64
#define ROWP 72       // LDS row pitch in shorts (64 data + 8 pad)
#define TAU 2.0e-3f   // validated r2-r7 (absmax 0); pass-A split-bf16 err ~3e-4

typedef __attribute__((ext_vector_type(8))) short short8;   // 8 bf16 = 4 VGPR
typedef __attribute__((ext_vector_type(4))) float floatx4;  // MFMA C/D

// ---- workspace layout (float idx) ----
// embT   f32[512*64]   [0, 32768)
// e2     f32[512]      [32768, 33280)
// e2d    f64[512]      [33280, 34304)   (byte 133120, 8-aligned)
// emb_hi bf16[512*64]  [34304, 50688)   (code-major, 64/row)
// emb_lo bf16[512*64]  [50688, 67072)
// cnt    int           67072
// list   int[262144]   from 67073

__device__ __forceinline__ void bf16split(float x, short& hi, short& lo) {
    unsigned u = __float_as_uint(x);
    unsigned h = (u + 0x7fffu + ((u >> 16) & 1u)) >> 16;   // RNE to bf16
    hi = (short)h;
    float hf = __uint_as_float(h << 16);
    float l = x - hf;                                      // exact in f32
    unsigned ul = __float_as_uint(l);
    lo = (short)((ul + 0x7fffu + ((ul >> 16) & 1u)) >> 16);
}

__global__ void prep_kernel(const float* __restrict__ w,
                            float* __restrict__ embT,
                            float* __restrict__ e2,
                            double* __restrict__ e2d,
                            short* __restrict__ emb_hi,
                            short* __restrict__ emb_lo,
                            int* __restrict__ cnt) {
    int tid = blockIdx.x * 256 + threadIdx.x;
    if (tid == 0) *cnt = 0;
    if (tid >= KCODES) return;
    float s = 0.0f; double sd = 0.0;
    for (int g = 0; g < GDIM; ++g) {
        float v = w[g * KCODES + tid];
        embT[tid * GDIM + g] = v;
        short h, l; bf16split(v, h, l);
        emb_hi[tid * GDIM + g] = h;
        emb_lo[tid * GDIM + g] = l;
        s = __fadd_rn(s, __fmul_rn(v, v));
        sd += (double)v * (double)v;
    }
    e2[tid] = s;
    e2d[tid] = sd;
}

// Pass A: full codebook resident in LDS (147 KB), staged ONCE per block, one
// barrier pair (r7 was barrier/latency-bound: 8 barriers, MfmaUtil 12.7%,
// VALUBusy 30%, nothing saturated). 512 blocks x 512 thr; wave owns 64
// positions (mt=4). Per nt-tile: 4 ds_read_b128 + 24 MFMA in 8 independent
// h/l chains + inline epilogue (acc never lives across nt).
// Layout map (hardware-validated by r7 passing): A[m=c][k=kt*32+q*8+j],
// B[k][n=c] same k-map, C/D row m=q*4+r col n=c.
__launch_bounds__(512, 2)
__global__ void vq_kernel(const float* __restrict__ x,
                          const float* __restrict__ embT,
                          const float* __restrict__ e2,
                          const short* __restrict__ emb_hi,
                          const short* __restrict__ emb_lo,
                          float* __restrict__ out_res,
                          float* __restrict__ out_arg,
                          int* __restrict__ cnt,
                          int* __restrict__ list) {
    __shared__ short s_hi[KCODES * ROWP];   // 73728 B
    __shared__ short s_lo[KCODES * ROWP];   // 73728 B
    __shared__ float s_e2c[KCODES];
    __shared__ int   s_arg[512];

    const int t = threadIdx.x;              // 0..511
    const int wid = t >> 6;                 // 0..7
    const int lane = t & 63;
    const int q = lane >> 4;                // quad
    const int c = lane & 15;                // col (code within tile / pos within m-tile)
    const int blk = blockIdx.x;
    const int grp = blk >> 7;               // 128 blocks per group
    const int sblk = (blk & 127) << 9;      // block's first position in group
    const int b = sblk >> 10;
    const int sidx0 = sblk & 1023;          // 0 or 512
    const int wpos = sidx0 + wid * 64;      // wave's first sidx

    // ---- stage full codebook: 512 rows x 8 uint4-units x 2 arrays ----
#pragma unroll
    for (int i = 0; i < 8; ++i) {
        int idx = i * 512 + t;              // 0..4095
        int rr = idx >> 3, uu = (idx & 7) * 8;
        *(uint4*)&s_hi[rr * ROWP + uu] = *(const uint4*)(emb_hi + rr * 64 + uu);
        *(uint4*)&s_lo[rr * ROWP + uu] = *(const uint4*)(emb_lo + rr * 64 + uu);
    }
    s_e2c[t] = e2[t];                       // t covers 0..511 exactly

    // ---- A fragments (overlaps staging; no barrier needed yet) ----
    const float* xbase = x + (size_t)b * 262144 + (size_t)grp * 65536 + wpos;
    short8 ahi[4][2], alo[4][2];
#pragma unroll
    for (int mt = 0; mt < 4; ++mt)
#pragma unroll
        for (int kt = 0; kt < 2; ++kt)
#pragma unroll
            for (int j = 0; j < 8; ++j) {
                float xv = xbase[(kt * 32 + q * 8 + j) * 1024 + mt * 16 + c];
                short h, l; bf16split(xv, h, l);
                ahi[mt][kt][j] = h; alo[mt][kt][j] = l;
            }

    __syncthreads();                        // the block's ONLY staging barrier

    float best[4][4], sec[4][4]; int argk[4][4];
#pragma unroll
    for (int mt = 0; mt < 4; ++mt)
#pragma unroll
        for (int r = 0; r < 4; ++r) { best[mt][r] = FLT_MAX; sec[mt][r] = FLT_MAX; argk[mt][r] = 0; }

    const floatx4 Z = (floatx4){0.f, 0.f, 0.f, 0.f};

#pragma unroll 4
    for (int nt = 0; nt < 32; ++nt) {
        const int off = (nt * 16 + c) * ROWP + q * 8;
        short8 bh0 = *(const short8*)&s_hi[off];
        short8 bh1 = *(const short8*)&s_hi[off + 32];
        short8 bl0 = *(const short8*)&s_lo[off];
        short8 bl1 = *(const short8*)&s_lo[off + 32];
        float se2 = s_e2c[nt * 16 + c];
        const int n = nt * 16 + c;
#pragma unroll
        for (int mt = 0; mt < 4; ++mt) {
            floatx4 h, l;                  // two independent chains per mt
            h = __builtin_amdgcn_mfma_f32_16x16x32_bf16(ahi[mt][0], bh0, Z, 0, 0, 0);
            l = __builtin_amdgcn_mfma_f32_16x16x32_bf16(alo[mt][0], bh0, Z, 0, 0, 0);
            h = __builtin_amdgcn_mfma_f32_16x16x32_bf16(ahi[mt][1], bh1, h, 0, 0, 0);
            l = __builtin_amdgcn_mfma_f32_16x16x32_bf16(ahi[mt][0], bl0, l, 0, 0, 0);
            l = __builtin_amdgcn_mfma_f32_16x16x32_bf16(alo[mt][1], bh1, l, 0, 0, 0);
            l = __builtin_amdgcn_mfma_f32_16x16x32_bf16(ahi[mt][1], bl1, l, 0, 0, 0);
#pragma unroll
            for (int r = 0; r < 4; ++r) {
                float s = __fmaf_rn(-2.0f, h[r], __fmaf_rn(-2.0f, l[r], se2));
                sec[mt][r] = fminf(fmaxf(s, best[mt][r]), sec[mt][r]);  // med3
                if (s < best[mt][r]) { best[mt][r] = s; argk[mt][r] = n; }
            }
        }
    }

    // ---- cross-lane merge over the 16 cols; ties -> gap 0 -> flag -> f64 fix
#pragma unroll
    for (int mt = 0; mt < 4; ++mt)
#pragma unroll
        for (int r = 0; r < 4; ++r) {
            float b_ = best[mt][r], s_ = sec[mt][r]; int a_ = argk[mt][r];
#pragma unroll
            for (int sh = 1; sh < 16; sh <<= 1) {
                float ob = __shfl_xor(b_, sh, 64);
                float os = __shfl_xor(s_, sh, 64);
                int   oa = __shfl_xor(a_, sh, 64);
                if (ob < b_) { s_ = fminf(b_, os); b_ = ob; a_ = oa; }
                else         { s_ = fminf(s_, ob); }
            }
            if (c == 0) {
                int p = mt * 16 + q * 4 + r;        // 0..63 within wave
                s_arg[wid * 64 + p] = a_;
                if (s_ - b_ <= TAU) {
                    int i = atomicAdd(cnt, 1);
                    list[i] = (grp << 16) | (sblk + wid * 64 + p);
                }
            }
        }
    __syncthreads();

    // argmin output: block's 512 positions, one coalesced store
    out_arg[(size_t)b * 4096 + (size_t)grp * 1024 + sidx0 + t] = (float)s_arg[t];

    // result output: wave's 64 positions, lane = position, 256B runs per store
    {
        int ac = s_arg[wid * 64 + lane];
        const float* ev = embT + (size_t)ac * GDIM;
        float* rp = out_res + (size_t)b * 262144 + (size_t)grp * 65536 + wpos + lane;
#pragma unroll
        for (int g = 0; g < GDIM; ++g)
            rp[(size_t)g * 1024] = ev[g] * 0.5f;
    }
}

// Pass B: exact f64 re-rank of flagged positions (compact list, r3-r5 proven;
// bitmap scan of r7 cost ~70us of non-vq time). Grid 2048 so flagged
// positions land ~1 per wave. Rank by s = e2d[k] - 2*dot.
__launch_bounds__(256)
__global__ void fix_kernel(const float* __restrict__ x,
                           const float* __restrict__ embT,
                           const double* __restrict__ e2d,
                           const int* __restrict__ cnt,
                           const int* __restrict__ list,
                           float* __restrict__ out_res,
                           float* __restrict__ out_arg) {
    const int lane = threadIdx.x & 63;
    const int wave = (blockIdx.x * blockDim.x + threadIdx.x) >> 6;
    const int nwaves = (gridDim.x * blockDim.x) >> 6;
    const int n = *cnt;

    for (int i = wave; i < n; i += nwaves) {
        const int gp = list[i];
        const int grp = gp >> 16;
        const int pos = gp & 0xffff;
        const int b = pos >> 10;
        const int sidx = pos & 1023;

        const float* xp = x + (size_t)b * 262144 + (size_t)grp * 65536 + sidx;
        float xr[GDIM];
#pragma unroll
        for (int g = 0; g < GDIM; ++g) xr[g] = xp[g * 1024];

        double bd = DBL_MAX;
        int bk = 0;
        for (int m = 0; m < KCODES / 64; ++m) {
            const int k = lane + m * 64;
            const float* er = embT + (size_t)k * GDIM;
            double dot = 0.0;
#pragma unroll
            for (int g = 0; g < GDIM; g += 4) {
                float4 e4 = *(const float4*)(er + g);
                dot += (double)xr[g + 0] * (double)e4.x;
                dot += (double)xr[g + 1] * (double)e4.y;
                dot += (double)xr[g + 2] * (double)e4.z;
                dot += (double)xr[g + 3] * (double)e4.w;
            }
            double s = e2d[k] - 2.0 * dot;
            if (s < bd) { bd = s; bk = k; }            // ascending k per lane
        }
        for (int off = 32; off > 0; off >>= 1) {       // lexicographic (s, k)
            double od = __shfl_down(bd, off, 64);
            int    ok = __shfl_down(bk, off, 64);
            if (od < bd || (od == bd && ok < bk)) { bd = od; bk = ok; }
        }
        bk = __shfl(bk, 0, 64);

        if (lane == 0)
            out_arg[(size_t)b * 4096 + (size_t)grp * 1024 + sidx] = (float)bk;
        out_res[(size_t)b * 262144 + (size_t)grp * 65536 + (size_t)lane * 1024 + sidx] =
            embT[(size_t)bk * GDIM + lane] * 0.5f;
    }
}

extern "C" void kernel_launch(void* const* d_in, const int* in_sizes, int n_in,
                              void* d_out, int out_size, void* d_ws, size_t ws_size,
                              hipStream_t stream) {
    const float* x = (const float*)d_in[0];      // (64,256,32,32) f32
    const float* w = (const float*)d_in[1];      // (64,512) f32
    float* out_res = (float*)d_out;              // 16777216 floats
    float* out_arg = (float*)d_out + 16777216;   // 262144 floats

    float*  embT   = (float*)d_ws;
    float*  e2     = embT + 32768;
    double* e2d    = (double*)((char*)d_ws + (size_t)33280 * 4);
    short*  emb_hi = (short*)((float*)d_ws + 34304);
    short*  emb_lo = (short*)((float*)d_ws + 50688);
    int*    cnt    = (int*)((float*)d_ws + 67072);
    int*    list   = cnt + 1;

    prep_kernel<<<2, 256, 0, stream>>>(w, embT, e2, e2d, emb_hi, emb_lo, cnt);
    vq_kernel<<<512, 512, 0, stream>>>(x, embT, e2, emb_hi, emb_lo,
                                       out_res, out_arg, cnt, list);
    fix_kernel<<<2048, 256, 0, stream>>>(x, embT, e2d, cnt, list, out_res, out_arg);
}